// Round 1
// baseline (177.622 us; speedup 1.0000x reference)
//
#include <hip/hip_runtime.h>

#define NBATCH 16
#define RSZ 128
#define ICH 64
#define OCH 64
#define MODES 16
#define TMODES 32
#define PI2F 6.283185307179586f

// ---------------- Stage 1: partial DFT along x ----------------
// A[row][w][i] = sum_x X[row][x][i] * e^{-2pi i w x/128}, w in [0,16)
__global__ __launch_bounds__(256) void k_dftx(const float* __restrict__ X,
                                              float2* __restrict__ A) {
  const int row = blockIdx.x;  // n*128 + y
  __shared__ float xs[RSZ * ICH];     // [x][i]  32 KB
  __shared__ float2 tw[MODES * RSZ];  // [w][x]  e^{-i theta}  16 KB
  const int tid = threadIdx.x;
  {
    const float4* src = (const float4*)(X + (size_t)row * RSZ * ICH);
    float4* dst = (float4*)xs;
#pragma unroll
    for (int k = 0; k < (RSZ * ICH / 4) / 256; ++k)
      dst[tid + k * 256] = src[tid + k * 256];
  }
  for (int k = tid; k < MODES * RSZ; k += 256) {
    int w = k >> 7, x = k & 127;
    int p = (w * x) & 127;
    float s, c;
    sincosf(PI2F * (float)p * (1.0f / 128.0f), &s, &c);
    tw[k] = make_float2(c, -s);
  }
  __syncthreads();
  const int it = tid & 31;  // i = it*2 + {0,1}
  const int wt = tid >> 5;  // w = wt*2 + {0,1}
  float2 a00 = {0.f, 0.f}, a01 = {0.f, 0.f}, a10 = {0.f, 0.f}, a11 = {0.f, 0.f};
  for (int x = 0; x < RSZ; ++x) {
    float2 xv = *(const float2*)&xs[x * ICH + it * 2];
    float2 t0 = tw[(wt * 2 + 0) * RSZ + x];
    float2 t1 = tw[(wt * 2 + 1) * RSZ + x];
    a00.x += xv.x * t0.x; a00.y += xv.x * t0.y;
    a01.x += xv.y * t0.x; a01.y += xv.y * t0.y;
    a10.x += xv.x * t1.x; a10.y += xv.x * t1.y;
    a11.x += xv.y * t1.x; a11.y += xv.y * t1.y;
  }
  float2* Arow = A + (size_t)row * MODES * ICH;
  *(float4*)&Arow[(wt * 2 + 0) * ICH + it * 2] = make_float4(a00.x, a00.y, a01.x, a01.y);
  *(float4*)&Arow[(wt * 2 + 1) * ICH + it * 2] = make_float4(a10.x, a10.y, a11.x, a11.y);
}

// ---------------- Stage 2: DFT along y (kept modes only) ----------------
// B[n][t][w][i] = sum_y A[n][y][w][i] * e^{-2pi i h_t y/128}, h_t = t<16 ? t : 96+t
__global__ __launch_bounds__(256) void k_dfty(const float2* __restrict__ A,
                                              float2* __restrict__ B) {
  const int b = blockIdx.x;
  const int ih = b & 1;         // which half of i
  const int w = (b >> 1) & 15;
  const int n = b >> 5;
  __shared__ float2 as_[RSZ * 32];   // [y][ii]  32 KB
  __shared__ float2 base[17 * RSZ];  // [k][y] = (cos,sin)(+2pi k y/128) 17 KB
  const int tid = threadIdx.x;
  for (int k = tid; k < RSZ * 32; k += 256) {
    int y = k >> 5, ii = k & 31;
    as_[k] = A[(((size_t)n * RSZ + y) * MODES + w) * ICH + ih * 32 + ii];
  }
  for (int k = tid; k < 17 * RSZ; k += 256) {
    int kk = k >> 7, y = k & 127;
    int p = (kk * y) & 127;
    float s, c;
    sincosf(PI2F * (float)p * (1.0f / 128.0f), &s, &c);
    base[k] = make_float2(c, s);
  }
  __syncthreads();
  const int it = tid & 15;  // ii = it*2
  const int tg = tid >> 4;  // t = tg*2 + {0,1}
  const int t0 = tg * 2, t1 = tg * 2 + 1;
  const float sg = (t0 < MODES) ? -1.f : 1.f;          // sign on sin for e^{-i h y}
  const int k0 = (t0 < MODES) ? t0 : 32 - t0;
  const int k1 = (t1 < MODES) ? t1 : 32 - t1;
  float2 acc00 = {0.f,0.f}, acc01 = {0.f,0.f}, acc10 = {0.f,0.f}, acc11 = {0.f,0.f};
  for (int y = 0; y < RSZ; ++y) {
    float4 av = *(const float4*)&as_[y * 32 + it * 2];  // (a0r,a0i,a1r,a1i)
    float2 e0 = base[k0 * RSZ + y];
    float2 e1 = base[k1 * RSZ + y];
    float ey0 = sg * e0.y, ey1 = sg * e1.y;
    acc00.x += av.x * e0.x - av.y * ey0;  acc00.y += av.x * ey0 + av.y * e0.x;
    acc01.x += av.z * e0.x - av.w * ey0;  acc01.y += av.z * ey0 + av.w * e0.x;
    acc10.x += av.x * e1.x - av.y * ey1;  acc10.y += av.x * ey1 + av.y * e1.x;
    acc11.x += av.z * e1.x - av.w * ey1;  acc11.y += av.z * ey1 + av.w * e1.x;
  }
  size_t b0 = (((size_t)n * TMODES + t0) * MODES + w) * ICH + ih * 32 + it * 2;
  size_t b1 = (((size_t)n * TMODES + t1) * MODES + w) * ICH + ih * 32 + it * 2;
  *(float4*)&B[b0] = make_float4(acc00.x, acc00.y, acc01.x, acc01.y);
  *(float4*)&B[b1] = make_float4(acc10.x, acc10.y, acc11.x, acc11.y);
}

// ---------------- Stage 3: mode mixing (in-place on B) ----------------
// C[n][t][w][o] = sum_i B[n][t][w][i] * W[i][o][mh][w],  W = fw0 (t<16) else fw1
__global__ __launch_bounds__(256) void k_mix(float2* __restrict__ BC,
                                             const float* __restrict__ fw0,
                                             const float* __restrict__ fw1) {
  const int t = blockIdx.x >> 4;
  const int w = blockIdx.x & 15;
  __shared__ float2 bs[NBATCH * ICH];  // [n][i]  8 KB
  __shared__ float2 wsld[ICH * OCH];   // [i][o]  32 KB
  const int tid = threadIdx.x;
  for (int k = tid; k < NBATCH * ICH; k += 256) {
    int n = k >> 6, i = k & 63;
    bs[k] = BC[(((size_t)n * TMODES + t) * MODES + w) * ICH + i];
  }
  const float* fw = (t < MODES) ? fw0 : fw1;
  const int mh = t & 15;
  for (int k = tid; k < ICH * OCH; k += 256) {
    // k = i*64 + o ; fw element (i,o,mh,w) at float offset ((i*64+o)*256 + mh*16 + w)*2
    wsld[k] = *(const float2*)(fw + ((size_t)k * 256 + (size_t)mh * 16 + w) * 2);
  }
  __syncthreads();
  const int o = tid & 63;
  const int ng = tid >> 6;  // n = ng*4 + q
  float2 acc[4] = {{0.f,0.f},{0.f,0.f},{0.f,0.f},{0.f,0.f}};
  for (int i = 0; i < ICH; ++i) {
    float2 wv = wsld[i * OCH + o];
#pragma unroll
    for (int q = 0; q < 4; ++q) {
      float2 bv = bs[(ng * 4 + q) * ICH + i];
      acc[q].x += bv.x * wv.x - bv.y * wv.y;
      acc[q].y += bv.x * wv.y + bv.y * wv.x;
    }
  }
#pragma unroll
  for (int q = 0; q < 4; ++q) {
    int n = ng * 4 + q;
    BC[(((size_t)n * TMODES + t) * MODES + w) * ICH + o] = acc[q];
  }
}

// ---------------- Stage 4: inverse DFT along y ----------------
// D[n][y][w][o] = sum_t C[n][t][w][o] * e^{+2pi i h_t y/128}
__global__ __launch_bounds__(256) void k_idfty(const float2* __restrict__ C,
                                               float2* __restrict__ D) {
  const int n = blockIdx.x >> 4;
  const int w = blockIdx.x & 15;
  __shared__ float2 cs[TMODES * OCH];  // [t][o]  16 KB
  __shared__ float2 base[17 * RSZ];    // 17 KB
  const int tid = threadIdx.x;
  for (int k = tid; k < TMODES * OCH; k += 256) {
    int t = k >> 6, o = k & 63;
    cs[k] = C[(((size_t)n * TMODES + t) * MODES + w) * ICH + o];
  }
  for (int k = tid; k < 17 * RSZ; k += 256) {
    int kk = k >> 7, y = k & 127;
    int p = (kk * y) & 127;
    float s, c;
    sincosf(PI2F * (float)p * (1.0f / 128.0f), &s, &c);
    base[k] = make_float2(c, s);
  }
  __syncthreads();
  const int o = tid & 63;
  const int yg = tid >> 6;  // y = yg*32 + q
  float2 acc[32];
#pragma unroll
  for (int q = 0; q < 32; ++q) acc[q] = make_float2(0.f, 0.f);
  for (int t = 0; t < TMODES; ++t) {
    float2 cv = cs[t * OCH + o];
    const float sg = (t < MODES) ? 1.f : -1.f;  // sign on sin for e^{+i h y}
    const int kk = (t < MODES) ? t : 32 - t;
    const float cx2 = sg * cv.x, cy2 = sg * cv.y;
#pragma unroll
    for (int q = 0; q < 32; ++q) {
      float2 e = base[kk * RSZ + yg * 32 + q];
      acc[q].x += cv.x * e.x - cy2 * e.y;
      acc[q].y += cx2 * e.y + cv.y * e.x;
    }
  }
  for (int q = 0; q < 32; ++q) {
    int y = yg * 32 + q;
    D[(((size_t)n * RSZ + y) * MODES + w) * OCH + o] = acc[q];
  }
}

// ---------------- Stage 5: inverse x (real) + residual GEMM + SiLU ----------------
__global__ __launch_bounds__(256) void k_final(const float* __restrict__ X,
                                               const float2* __restrict__ D,
                                               const float* __restrict__ w_res,
                                               const float* __restrict__ b_res,
                                               float* __restrict__ out) {
  const int row = blockIdx.x;  // n*128 + y
  const int XS_STRIDE = 132;
  __shared__ float xs[ICH * 132];      // [i][x] padded  33.8 KB
  __shared__ float wr[ICH * OCH];      // [i][o]  16 KB
  __shared__ float2 dsc[MODES * OCH];  // [w][o] pre-scaled  8 KB
  __shared__ float2 tw[MODES * RSZ];   // [w][x] e^{+i}  16 KB
  __shared__ float br[OCH];
  const int tid = threadIdx.x;
  {
    const float4* src = (const float4*)(X + (size_t)row * RSZ * ICH);
#pragma unroll
    for (int j = 0; j < 8; ++j) {
      int k = tid + j * 256;  // x = k>>4, i4 = (k&15)*4
      float4 v = src[k];
      int x = k >> 4, i4 = (k & 15) * 4;
      xs[(i4 + 0) * XS_STRIDE + x] = v.x;
      xs[(i4 + 1) * XS_STRIDE + x] = v.y;
      xs[(i4 + 2) * XS_STRIDE + x] = v.z;
      xs[(i4 + 3) * XS_STRIDE + x] = v.w;
    }
  }
  for (int k = tid; k < ICH * OCH; k += 256) wr[k] = w_res[k];
  if (tid < OCH) br[tid] = b_res[tid];
  for (int k = tid; k < MODES * OCH; k += 256) {
    int w = k >> 6;
    float2 d = D[((size_t)row * MODES + w) * OCH + (k & 63)];
    float sc = (1.f / 16384.f) * ((w == 0) ? 1.f : 2.f);
    dsc[k] = make_float2(d.x * sc, d.y * sc);
  }
  for (int k = tid; k < MODES * RSZ; k += 256) {
    int w = k >> 7, x = k & 127;
    int p = (w * x) & 127;
    float s, c;
    sincosf(PI2F * (float)p * (1.0f / 128.0f), &s, &c);
    tw[k] = make_float2(c, s);
  }
  __syncthreads();
  const int xt = tid >> 3;  // x = xt*4 + a
  const int ot = tid & 7;   // o = ot*8 + b
  float acc[4][8];
#pragma unroll
  for (int a2 = 0; a2 < 4; ++a2)
#pragma unroll
    for (int b2 = 0; b2 < 8; ++b2) acc[a2][b2] = br[ot * 8 + b2];
  // residual GEMM
  for (int i = 0; i < ICH; ++i) {
    float4 xv = *(const float4*)&xs[i * XS_STRIDE + xt * 4];
    float4 w0 = *(const float4*)&wr[i * OCH + ot * 8];
    float4 w1 = *(const float4*)&wr[i * OCH + ot * 8 + 4];
    float xa[4] = {xv.x, xv.y, xv.z, xv.w};
    float wv[8] = {w0.x, w0.y, w0.z, w0.w, w1.x, w1.y, w1.z, w1.w};
#pragma unroll
    for (int a2 = 0; a2 < 4; ++a2)
#pragma unroll
      for (int b2 = 0; b2 < 8; ++b2) acc[a2][b2] += xa[a2] * wv[b2];
  }
  // spectral inverse along x: acc += Re(D[w,o] * e^{+2pi i w x/128}) (scales folded)
  for (int w = 0; w < MODES; ++w) {
    float4 e01 = *(const float4*)&tw[w * RSZ + xt * 4];
    float4 e23 = *(const float4*)&tw[w * RSZ + xt * 4 + 2];
    float2 ea[4] = {{e01.x, e01.y}, {e01.z, e01.w}, {e23.x, e23.y}, {e23.z, e23.w}};
    float2 dv[8];
#pragma unroll
    for (int b2 = 0; b2 < 4; ++b2) {
      float4 dd = *(const float4*)&dsc[w * OCH + ot * 8 + b2 * 2];
      dv[b2 * 2 + 0] = make_float2(dd.x, dd.y);
      dv[b2 * 2 + 1] = make_float2(dd.z, dd.w);
    }
#pragma unroll
    for (int a2 = 0; a2 < 4; ++a2)
#pragma unroll
      for (int b2 = 0; b2 < 8; ++b2)
        acc[a2][b2] += dv[b2].x * ea[a2].x - dv[b2].y * ea[a2].y;
  }
  float* orow = out + (size_t)row * RSZ * OCH;
#pragma unroll
  for (int a2 = 0; a2 < 4; ++a2) {
    int x = xt * 4 + a2;
    float vv[8];
#pragma unroll
    for (int b2 = 0; b2 < 8; ++b2) {
      float v = acc[a2][b2];
      vv[b2] = v / (1.f + __expf(-v));
    }
    *(float4*)&orow[x * OCH + ot * 8 + 0] = make_float4(vv[0], vv[1], vv[2], vv[3]);
    *(float4*)&orow[x * OCH + ot * 8 + 4] = make_float4(vv[4], vv[5], vv[6], vv[7]);
  }
}

extern "C" void kernel_launch(void* const* d_in, const int* in_sizes, int n_in,
                              void* d_out, int out_size, void* d_ws, size_t ws_size,
                              hipStream_t stream) {
  (void)in_sizes; (void)n_in; (void)out_size; (void)ws_size;
  const float* X = (const float*)d_in[0];
  const float* w_res = (const float*)d_in[1];
  const float* b_res = (const float*)d_in[2];
  const float* fw0 = (const float*)d_in[3];
  const float* fw1 = (const float*)d_in[4];
  float* out = (float*)d_out;
  float2* bufA = (float2*)d_ws;                              // 16 MB: A then D (aliased)
  float2* bufB = bufA + (size_t)NBATCH * RSZ * MODES * ICH;  // 4 MB: B, mixed in place
  k_dftx<<<NBATCH * RSZ, 256, 0, stream>>>(X, bufA);
  k_dfty<<<NBATCH * MODES * 2, 256, 0, stream>>>(bufA, bufB);
  k_mix<<<TMODES * MODES, 256, 0, stream>>>(bufB, fw0, fw1);
  k_idfty<<<NBATCH * MODES, 256, 0, stream>>>(bufB, bufA);
  k_final<<<NBATCH * RSZ, 256, 0, stream>>>(X, bufA, w_res, b_res, out);
}

// Round 2
// 124.931 us; speedup vs baseline: 1.4218x; 1.4218x over previous
//
#include <hip/hip_runtime.h>

#define NBATCH 16
#define RSZ 128
#define ICH 64
#define OCH 64
#define MODES 16
#define TMODES 32
#define PI2F 6.283185307179586f

typedef float f32x4 __attribute__((ext_vector_type(4)));
typedef short bf16x8 __attribute__((ext_vector_type(8)));

static __device__ __forceinline__ ushort f2bf(float f) {
  union { float f; unsigned u; } v;
  v.f = f;
  unsigned r = v.u + 0x7FFFu + ((v.u >> 16) & 1u);
  return (ushort)(r >> 16);
}

// ---------------- Stage 1: partial DFT along x (MFMA) ----------------
// Are/Aim[row][w][i] = sum_x X[row][x][i] * e^{-2pi i w x/128}, w in [0,16)
// Per row: A(32x64) = T(32x128) @ Xrow(128x64), T rows 2w=cos, 2w+1=-sin.
__global__ __launch_bounds__(256) void k_dftx(const float* __restrict__ X,
                                              float* __restrict__ Are,
                                              float* __restrict__ Aim) {
  __shared__ ushort Tm[32][136];       // [m][x] bf16, pad->2-way max
  __shared__ ushort XT[4][64][136];    // per-wave row: [i][x ^ swz(i)]
  const int tid = threadIdx.x;
  const int row0 = blockIdx.x * 4;
  // twiddles (shared by all 4 rows)
  {
    int w = tid >> 4, xseg = (tid & 15) * 8;
    for (int e = 0; e < 8; ++e) {
      int x = xseg + e;
      int p = (w * x) & 127;
      float s, c;
      sincosf(PI2F * (float)p * (1.0f / 128.0f), &s, &c);
      Tm[2 * w][x] = f2bf(c);
      Tm[2 * w + 1][x] = f2bf(-s);
    }
  }
  // stage X transposed to bf16 via 4x4 register tiles
  {
    const int rr = tid >> 6, lane = tid & 63;
    const float* Xr = X + (size_t)(row0 + rr) * RSZ * ICH;
    for (int j = 0; j < 8; ++j) {
      int t = lane + 64 * j;
      int i0 = (t & 15) * 4, x0 = (t >> 4) * 4;
      float4 r0 = *(const float4*)&Xr[(x0 + 0) * ICH + i0];
      float4 r1 = *(const float4*)&Xr[(x0 + 1) * ICH + i0];
      float4 r2 = *(const float4*)&Xr[(x0 + 2) * ICH + i0];
      float4 r3 = *(const float4*)&Xr[(x0 + 3) * ICH + i0];
#pragma unroll
      for (int p = 0; p < 4; ++p) {
        int i = i0 + p;
        int col = x0 ^ ((((i) >> 2) & 7) << 3);
        ushort4 pk;
        pk.x = f2bf(((const float*)&r0)[p]);
        pk.y = f2bf(((const float*)&r1)[p]);
        pk.z = f2bf(((const float*)&r2)[p]);
        pk.w = f2bf(((const float*)&r3)[p]);
        *(ushort4*)&XT[rr][i][col] = pk;
      }
    }
  }
  __syncthreads();
  const int wid = tid >> 6, lane = tid & 63;
  const int lr = lane & 15, lk = lane >> 4;
  f32x4 acc[2][4];
#pragma unroll
  for (int mt = 0; mt < 2; ++mt)
#pragma unroll
    for (int nt = 0; nt < 4; ++nt) acc[mt][nt] = (f32x4)(0.f);
#pragma unroll
  for (int kt = 0; kt < 4; ++kt) {
    int kb = kt * 32 + lk * 8;
    bf16x8 a0 = *(const bf16x8*)&Tm[lr][kb];
    bf16x8 a1 = *(const bf16x8*)&Tm[16 + lr][kb];
    bf16x8 b[4];
#pragma unroll
    for (int nt = 0; nt < 4; ++nt) {
      int i = nt * 16 + lr;
      int col = kb ^ (((i >> 2) & 7) << 3);
      b[nt] = *(const bf16x8*)&XT[wid][i][col];
    }
#pragma unroll
    for (int nt = 0; nt < 4; ++nt) {
      acc[0][nt] = __builtin_amdgcn_mfma_f32_16x16x32_bf16(a0, b[nt], acc[0][nt], 0, 0, 0);
      acc[1][nt] = __builtin_amdgcn_mfma_f32_16x16x32_bf16(a1, b[nt], acc[1][nt], 0, 0, 0);
    }
  }
  const int row = row0 + wid;
#pragma unroll
  for (int mt = 0; mt < 2; ++mt)
#pragma unroll
    for (int q = 0; q < 4; ++q) {
      int m = mt * 16 + lk * 4 + q;
      int w = m >> 1, c = m & 1;
      float* plane = c ? Aim : Are;
#pragma unroll
      for (int nt = 0; nt < 4; ++nt) {
        int i = nt * 16 + lr;
        plane[((size_t)row * MODES + w) * ICH + i] = acc[mt][nt][q];
      }
    }
}

// ---------------- Stage 2: DFT along y (kept modes only) ----------------
__global__ __launch_bounds__(256) void k_dfty(const float* __restrict__ Are,
                                              const float* __restrict__ Aim,
                                              float2* __restrict__ B) {
  const int b = blockIdx.x;
  const int ih = b & 1;
  const int w = (b >> 1) & 15;
  const int n = b >> 5;
  __shared__ float2 as_[RSZ * 32];
  __shared__ float2 base[17 * RSZ];
  const int tid = threadIdx.x;
  for (int k = tid; k < RSZ * 32; k += 256) {
    int y = k >> 5, ii = k & 31;
    size_t off = (((size_t)n * RSZ + y) * MODES + w) * ICH + ih * 32 + ii;
    as_[k] = make_float2(Are[off], Aim[off]);
  }
  for (int k = tid; k < 17 * RSZ; k += 256) {
    int kk = k >> 7, y = k & 127;
    int p = (kk * y) & 127;
    float s, c;
    sincosf(PI2F * (float)p * (1.0f / 128.0f), &s, &c);
    base[k] = make_float2(c, s);
  }
  __syncthreads();
  const int it = tid & 15;
  const int tg = tid >> 4;
  const int t0 = tg * 2, t1 = tg * 2 + 1;
  const float sg = (t0 < MODES) ? -1.f : 1.f;
  const int k0 = (t0 < MODES) ? t0 : 32 - t0;
  const int k1 = (t1 < MODES) ? t1 : 32 - t1;
  float2 acc00 = {0.f,0.f}, acc01 = {0.f,0.f}, acc10 = {0.f,0.f}, acc11 = {0.f,0.f};
  for (int y = 0; y < RSZ; ++y) {
    float4 av = *(const float4*)&as_[y * 32 + it * 2];
    float2 e0 = base[k0 * RSZ + y];
    float2 e1 = base[k1 * RSZ + y];
    float ey0 = sg * e0.y, ey1 = sg * e1.y;
    acc00.x += av.x * e0.x - av.y * ey0;  acc00.y += av.x * ey0 + av.y * e0.x;
    acc01.x += av.z * e0.x - av.w * ey0;  acc01.y += av.z * ey0 + av.w * e0.x;
    acc10.x += av.x * e1.x - av.y * ey1;  acc10.y += av.x * ey1 + av.y * e1.x;
    acc11.x += av.z * e1.x - av.w * ey1;  acc11.y += av.z * ey1 + av.w * e1.x;
  }
  size_t b0 = (((size_t)n * TMODES + t0) * MODES + w) * ICH + ih * 32 + it * 2;
  size_t b1 = (((size_t)n * TMODES + t1) * MODES + w) * ICH + ih * 32 + it * 2;
  *(float4*)&B[b0] = make_float4(acc00.x, acc00.y, acc01.x, acc01.y);
  *(float4*)&B[b1] = make_float4(acc10.x, acc10.y, acc11.x, acc11.y);
}

// ---------------- Stage 3: mode mixing (in-place on B) ----------------
__global__ __launch_bounds__(256) void k_mix(float2* __restrict__ BC,
                                             const float* __restrict__ fw0,
                                             const float* __restrict__ fw1) {
  const int t = blockIdx.x >> 4;
  const int w = blockIdx.x & 15;
  __shared__ float2 bs[NBATCH * ICH];
  __shared__ float2 wsld[ICH * OCH];
  const int tid = threadIdx.x;
  for (int k = tid; k < NBATCH * ICH; k += 256) {
    int n = k >> 6, i = k & 63;
    bs[k] = BC[(((size_t)n * TMODES + t) * MODES + w) * ICH + i];
  }
  const float* fw = (t < MODES) ? fw0 : fw1;
  const int mh = t & 15;
  for (int k = tid; k < ICH * OCH; k += 256) {
    wsld[k] = *(const float2*)(fw + ((size_t)k * 256 + (size_t)mh * 16 + w) * 2);
  }
  __syncthreads();
  const int o = tid & 63;
  const int ng = tid >> 6;
  float2 acc[4] = {{0.f,0.f},{0.f,0.f},{0.f,0.f},{0.f,0.f}};
  for (int i = 0; i < ICH; ++i) {
    float2 wv = wsld[i * OCH + o];
#pragma unroll
    for (int q = 0; q < 4; ++q) {
      float2 bv = bs[(ng * 4 + q) * ICH + i];
      acc[q].x += bv.x * wv.x - bv.y * wv.y;
      acc[q].y += bv.x * wv.y + bv.y * wv.x;
    }
  }
#pragma unroll
  for (int q = 0; q < 4; ++q) {
    int n = ng * 4 + q;
    BC[(((size_t)n * TMODES + t) * MODES + w) * ICH + o] = acc[q];
  }
}

// ---------------- Stage 4: inverse DFT along y (scale folded) ----------------
__global__ __launch_bounds__(256) void k_idfty(const float2* __restrict__ C,
                                               float2* __restrict__ D) {
  const int n = blockIdx.x >> 4;
  const int w = blockIdx.x & 15;
  __shared__ float2 cs[TMODES * OCH];
  __shared__ float2 base[17 * RSZ];
  const int tid = threadIdx.x;
  for (int k = tid; k < TMODES * OCH; k += 256) {
    int t = k >> 6, o = k & 63;
    cs[k] = C[(((size_t)n * TMODES + t) * MODES + w) * ICH + o];
  }
  for (int k = tid; k < 17 * RSZ; k += 256) {
    int kk = k >> 7, y = k & 127;
    int p = (kk * y) & 127;
    float s, c;
    sincosf(PI2F * (float)p * (1.0f / 128.0f), &s, &c);
    base[k] = make_float2(c, s);
  }
  __syncthreads();
  const int o = tid & 63;
  const int yg = tid >> 6;
  const float sc = (w == 0) ? (1.f / 16384.f) : (2.f / 16384.f);
  float2 acc[32];
#pragma unroll
  for (int q = 0; q < 32; ++q) acc[q] = make_float2(0.f, 0.f);
  for (int t = 0; t < TMODES; ++t) {
    float2 cv = cs[t * OCH + o];
    const float sg = (t < MODES) ? 1.f : -1.f;
    const int kk = (t < MODES) ? t : 32 - t;
    const float cx2 = sg * cv.x, cy2 = sg * cv.y;
#pragma unroll
    for (int q = 0; q < 32; ++q) {
      float2 e = base[kk * RSZ + yg * 32 + q];
      acc[q].x += cv.x * e.x - cy2 * e.y;
      acc[q].y += cx2 * e.y + cv.y * e.x;
    }
  }
  for (int q = 0; q < 32; ++q) {
    int y = yg * 32 + q;
    D[(((size_t)n * RSZ + y) * MODES + w) * OCH + o] =
        make_float2(acc[q].x * sc, acc[q].y * sc);
  }
}

// ---------------- Stage 5: fused [X|E] @ [WresT;Dsc] + bias + SiLU (MFMA) ----------------
__global__ __launch_bounds__(256) void k_final(const float* __restrict__ X,
                                               const float2* __restrict__ D,
                                               const float* __restrict__ w_res,
                                               const float* __restrict__ b_res,
                                               float* __restrict__ out) {
  __shared__ ushort Ac[128][104];  // [x][k] k: 0..63 = X, 64..95 = E twiddles
  __shared__ ushort Bc[64][104];   // [o][k] k: 0..63 = w_res^T, 64..95 = Dsc
  __shared__ float br[64];
  const int tid = threadIdx.x;
  const int row = blockIdx.x;  // n*128 + y
  const float* Xr = X + (size_t)row * RSZ * ICH;
  // (a) X -> Ac[x][0..63] bf16
#pragma unroll
  for (int j = 0; j < 8; ++j) {
    int k = tid + j * 256;
    int x = k >> 4, i0 = (k & 15) * 4;
    float4 v = *(const float4*)&Xr[x * ICH + i0];
    ushort4 pk;
    pk.x = f2bf(v.x); pk.y = f2bf(v.y); pk.z = f2bf(v.z); pk.w = f2bf(v.w);
    *(ushort4*)&Ac[x][i0] = pk;
  }
  // (b) E twiddles -> Ac[x][64+2w]=cos, [64+2w+1]=-sin  (e^{+i}, minus folds the complex mul)
  {
    int x = tid >> 1, half = tid & 1;
#pragma unroll
    for (int w2 = 0; w2 < 8; ++w2) {
      int w = half * 8 + w2;
      int p = (w * x) & 127;
      float s, c;
      sincosf(PI2F * (float)p * (1.0f / 128.0f), &s, &c);
      Ac[x][64 + 2 * w] = f2bf(c);
      Ac[x][64 + 2 * w + 1] = f2bf(-s);
    }
  }
  // (c) w_res^T -> Bc[o][0..63]
#pragma unroll
  for (int j = 0; j < 4; ++j) {
    int k = tid + j * 256;
    int i = k >> 4, o0 = (k & 15) * 4;
    float4 v = *(const float4*)&w_res[i * OCH + o0];
    Bc[o0 + 0][i] = f2bf(v.x);
    Bc[o0 + 1][i] = f2bf(v.y);
    Bc[o0 + 2][i] = f2bf(v.z);
    Bc[o0 + 3][i] = f2bf(v.w);
  }
  // (d) Dsc (pre-scaled by k_idfty) -> Bc[o][64+2w]=re, [64+2w+1]=im
#pragma unroll
  for (int j = 0; j < 4; ++j) {
    int k = tid + j * 256;
    int w = k >> 6, o = k & 63;
    float2 d = D[((size_t)row * MODES + w) * OCH + o];
    ushort2 pk;
    pk.x = f2bf(d.x); pk.y = f2bf(d.y);
    *(ushort2*)&Bc[o][64 + 2 * w] = pk;
  }
  if (tid < 64) br[tid] = b_res[tid];
  __syncthreads();
  const int wid = tid >> 6, lane = tid & 63;
  const int lr = lane & 15, lk = lane >> 4;
  f32x4 acc[2][4];
#pragma unroll
  for (int mi = 0; mi < 2; ++mi)
#pragma unroll
    for (int nt = 0; nt < 4; ++nt) acc[mi][nt] = (f32x4)(0.f);
#pragma unroll
  for (int kt = 0; kt < 3; ++kt) {
    int kb = kt * 32 + lk * 8;
    bf16x8 a0 = *(const bf16x8*)&Ac[(wid * 2 + 0) * 16 + lr][kb];
    bf16x8 a1 = *(const bf16x8*)&Ac[(wid * 2 + 1) * 16 + lr][kb];
    bf16x8 b[4];
#pragma unroll
    for (int nt = 0; nt < 4; ++nt) b[nt] = *(const bf16x8*)&Bc[nt * 16 + lr][kb];
#pragma unroll
    for (int nt = 0; nt < 4; ++nt) {
      acc[0][nt] = __builtin_amdgcn_mfma_f32_16x16x32_bf16(a0, b[nt], acc[0][nt], 0, 0, 0);
      acc[1][nt] = __builtin_amdgcn_mfma_f32_16x16x32_bf16(a1, b[nt], acc[1][nt], 0, 0, 0);
    }
  }
  float* orow = out + (size_t)row * RSZ * OCH;
#pragma unroll
  for (int mi = 0; mi < 2; ++mi)
#pragma unroll
    for (int nt = 0; nt < 4; ++nt)
#pragma unroll
      for (int q = 0; q < 4; ++q) {
        int x = (wid * 2 + mi) * 16 + lk * 4 + q;
        int o = nt * 16 + lr;
        float v = acc[mi][nt][q] + br[o];
        orow[x * OCH + o] = v / (1.f + __expf(-v));
      }
}

extern "C" void kernel_launch(void* const* d_in, const int* in_sizes, int n_in,
                              void* d_out, int out_size, void* d_ws, size_t ws_size,
                              hipStream_t stream) {
  (void)in_sizes; (void)n_in; (void)out_size; (void)ws_size;
  const float* X = (const float*)d_in[0];
  const float* w_res = (const float*)d_in[1];
  const float* b_res = (const float*)d_in[2];
  const float* fw0 = (const float*)d_in[3];
  const float* fw1 = (const float*)d_in[4];
  float* out = (float*)d_out;
  float* wsf = (float*)d_ws;
  const size_t PLANE = (size_t)NBATCH * RSZ * MODES * ICH;  // 2.1M floats
  float* Are = wsf;
  float* Aim = wsf + PLANE;
  float2* bufB = (float2*)(wsf + 2 * PLANE);  // 4.2 MB (B, mixed in place)
  float2* Dbuf = (float2*)wsf;                // reuses A region after dfty
  k_dftx<<<NBATCH * RSZ / 4, 256, 0, stream>>>(X, Are, Aim);
  k_dfty<<<NBATCH * MODES * 2, 256, 0, stream>>>(Are, Aim, bufB);
  k_mix<<<TMODES * MODES, 256, 0, stream>>>(bufB, fw0, fw1);
  k_idfty<<<NBATCH * MODES, 256, 0, stream>>>(bufB, Dbuf);
  k_final<<<NBATCH * RSZ, 256, 0, stream>>>(X, Dbuf, w_res, b_res, out);
}

// Round 3
// 91.774 us; speedup vs baseline: 1.9354x; 1.3613x over previous
//
#include <hip/hip_runtime.h>

#define NBATCH 16
#define RSZ 128
#define ICH 64
#define OCH 64
#define MODES 16
#define TMODES 32
#define PI2F 6.283185307179586f

typedef float f32x4 __attribute__((ext_vector_type(4)));
typedef short bf16x8 __attribute__((ext_vector_type(8)));

static __device__ __forceinline__ ushort f2bf(float f) {
  union { float f; unsigned u; } v;
  v.f = f;
  unsigned r = v.u + 0x7FFFu + ((v.u >> 16) & 1u);
  return (ushort)(r >> 16);
}

// ---------------- Stage 1: partial DFT along x (MFMA) ----------------
__global__ __launch_bounds__(256) void k_dftx(const float* __restrict__ X,
                                              float* __restrict__ Are,
                                              float* __restrict__ Aim) {
  __shared__ ushort Tm[32][136];
  __shared__ ushort XT[4][64][136];
  const int tid = threadIdx.x;
  const int row0 = blockIdx.x * 4;
  {
    int w = tid >> 4, xseg = (tid & 15) * 8;
    for (int e = 0; e < 8; ++e) {
      int x = xseg + e;
      int p = (w * x) & 127;
      float s, c;
      sincosf(PI2F * (float)p * (1.0f / 128.0f), &s, &c);
      Tm[2 * w][x] = f2bf(c);
      Tm[2 * w + 1][x] = f2bf(-s);
    }
  }
  {
    const int rr = tid >> 6, lane = tid & 63;
    const float* Xr = X + (size_t)(row0 + rr) * RSZ * ICH;
    for (int j = 0; j < 8; ++j) {
      int t = lane + 64 * j;
      int i0 = (t & 15) * 4, x0 = (t >> 4) * 4;
      float4 r0 = *(const float4*)&Xr[(x0 + 0) * ICH + i0];
      float4 r1 = *(const float4*)&Xr[(x0 + 1) * ICH + i0];
      float4 r2 = *(const float4*)&Xr[(x0 + 2) * ICH + i0];
      float4 r3 = *(const float4*)&Xr[(x0 + 3) * ICH + i0];
#pragma unroll
      for (int p = 0; p < 4; ++p) {
        int i = i0 + p;
        int col = x0 ^ ((((i) >> 2) & 7) << 3);
        ushort4 pk;
        pk.x = f2bf(((const float*)&r0)[p]);
        pk.y = f2bf(((const float*)&r1)[p]);
        pk.z = f2bf(((const float*)&r2)[p]);
        pk.w = f2bf(((const float*)&r3)[p]);
        *(ushort4*)&XT[rr][i][col] = pk;
      }
    }
  }
  __syncthreads();
  const int wid = tid >> 6, lane = tid & 63;
  const int lr = lane & 15, lk = lane >> 4;
  f32x4 acc[2][4];
#pragma unroll
  for (int mt = 0; mt < 2; ++mt)
#pragma unroll
    for (int nt = 0; nt < 4; ++nt) acc[mt][nt] = (f32x4)(0.f);
#pragma unroll
  for (int kt = 0; kt < 4; ++kt) {
    int kb = kt * 32 + lk * 8;
    bf16x8 a0 = *(const bf16x8*)&Tm[lr][kb];
    bf16x8 a1 = *(const bf16x8*)&Tm[16 + lr][kb];
    bf16x8 b[4];
#pragma unroll
    for (int nt = 0; nt < 4; ++nt) {
      int i = nt * 16 + lr;
      int col = kb ^ (((i >> 2) & 7) << 3);
      b[nt] = *(const bf16x8*)&XT[wid][i][col];
    }
#pragma unroll
    for (int nt = 0; nt < 4; ++nt) {
      acc[0][nt] = __builtin_amdgcn_mfma_f32_16x16x32_bf16(a0, b[nt], acc[0][nt], 0, 0, 0);
      acc[1][nt] = __builtin_amdgcn_mfma_f32_16x16x32_bf16(a1, b[nt], acc[1][nt], 0, 0, 0);
    }
  }
  const int row = row0 + wid;
#pragma unroll
  for (int mt = 0; mt < 2; ++mt)
#pragma unroll
    for (int q = 0; q < 4; ++q) {
      int m = mt * 16 + lk * 4 + q;
      int w = m >> 1, c = m & 1;
      float* plane = c ? Aim : Are;
#pragma unroll
      for (int nt = 0; nt < 4; ++nt) {
        int i = nt * 16 + lr;
        plane[((size_t)row * MODES + w) * ICH + i] = acc[mt][nt][q];
      }
    }
}

// ---------------- Stage 2: y-DFT via MFMA (K-stacked complex) ----------------
// Bstack(64x64) = T1(64x256) @ Astack(256x64) per (n,w).
// T1 rows m<32: Bre[t=m] = [cos | +sin]; m>=32: Bim[t=m-32] = [-sin | cos].
__global__ __launch_bounds__(512) void k_dfty(const float* __restrict__ Are,
                                              const float* __restrict__ Aim,
                                              float2* __restrict__ B) {
  const int n = blockIdx.x >> 4;
  const int w = blockIdx.x & 15;
  __shared__ float2 ut[128];
  __shared__ ushort T1[64][264];
  __shared__ ushort As[64][264];  // [i][k], k = y + 128*plane
  const int tid = threadIdx.x;
  if (tid < 128) {
    float s, c;
    sincosf(PI2F * (float)tid * (1.0f / 128.0f), &s, &c);
    ut[tid] = make_float2(c, s);
  }
  __syncthreads();
#pragma unroll
  for (int e = 0; e < 32; ++e) {
    int idx = e * 512 + tid;           // 16384 entries
    int m = idx >> 8, k = idx & 255;
    int y = k & 127, pl = k >> 7;
    int t = m & 31, imr = m >> 5;
    int h = (t < 16) ? t : (t + 96);
    float2 u = ut[(h * y) & 127];
    float val;
    if (!imr) val = pl ? u.y : u.x;    // [cos | sin]
    else      val = pl ? u.x : -u.y;   // [-sin | cos]
    T1[m][k] = f2bf(val);
  }
  // stage Astack transposed: 4x4 register tiles, 2 tiles/thread
#pragma unroll
  for (int e = 0; e < 2; ++e) {
    int tt = e * 512 + tid;            // 1024 tiles of 4x4
    int pl = tt >> 9, r = tt & 511;
    int i0 = (r & 15) * 4, y0 = (r >> 4) * 4;
    const float* P = pl ? Aim : Are;
    const float* base = P + (((size_t)(n * RSZ + y0) * MODES + w) * ICH + i0);
    float4 r0 = *(const float4*)(base + 0 * MODES * ICH);
    float4 r1 = *(const float4*)(base + 1 * MODES * ICH);
    float4 r2 = *(const float4*)(base + 2 * MODES * ICH);
    float4 r3 = *(const float4*)(base + 3 * MODES * ICH);
#pragma unroll
    for (int p = 0; p < 4; ++p) {
      ushort4 pk;
      pk.x = f2bf(((const float*)&r0)[p]);
      pk.y = f2bf(((const float*)&r1)[p]);
      pk.z = f2bf(((const float*)&r2)[p]);
      pk.w = f2bf(((const float*)&r3)[p]);
      *(ushort4*)&As[i0 + p][pl * 128 + y0] = pk;
    }
  }
  __syncthreads();
  const int wid = tid >> 6, lane = tid & 63;
  const int lr = lane & 15, lk = lane >> 4;
  const int mt = wid >> 1, nh = wid & 1;
  f32x4 acc[2];
  acc[0] = (f32x4)(0.f);
  acc[1] = (f32x4)(0.f);
#pragma unroll
  for (int kt = 0; kt < 8; ++kt) {
    int kb = kt * 32 + lk * 8;
    bf16x8 a = *(const bf16x8*)&T1[mt * 16 + lr][kb];
    bf16x8 b0 = *(const bf16x8*)&As[(nh * 2 + 0) * 16 + lr][kb];
    bf16x8 b1 = *(const bf16x8*)&As[(nh * 2 + 1) * 16 + lr][kb];
    acc[0] = __builtin_amdgcn_mfma_f32_16x16x32_bf16(a, b0, acc[0], 0, 0, 0);
    acc[1] = __builtin_amdgcn_mfma_f32_16x16x32_bf16(a, b1, acc[1], 0, 0, 0);
  }
  float* Bf = (float*)B;
#pragma unroll
  for (int nt2 = 0; nt2 < 2; ++nt2)
#pragma unroll
    for (int q = 0; q < 4; ++q) {
      int m = mt * 16 + lk * 4 + q;
      int t = m & 31, pl = m >> 5;
      int i = (nh * 2 + nt2) * 16 + lr;
      Bf[((((size_t)n * TMODES + t) * MODES + w) * ICH + i) * 2 + pl] = acc[nt2][q];
    }
}

// ---------------- Stage 3: mode mixing (in-place on B) ----------------
__global__ __launch_bounds__(256) void k_mix(float2* __restrict__ BC,
                                             const float* __restrict__ fw0,
                                             const float* __restrict__ fw1) {
  const int t = blockIdx.x >> 4;
  const int w = blockIdx.x & 15;
  __shared__ float2 bs[NBATCH * ICH];
  __shared__ float2 wsld[ICH * OCH];
  const int tid = threadIdx.x;
  for (int k = tid; k < NBATCH * ICH; k += 256) {
    int n = k >> 6, i = k & 63;
    bs[k] = BC[(((size_t)n * TMODES + t) * MODES + w) * ICH + i];
  }
  const float* fw = (t < MODES) ? fw0 : fw1;
  const int mh = t & 15;
  for (int k = tid; k < ICH * OCH; k += 256) {
    wsld[k] = *(const float2*)(fw + ((size_t)k * 256 + (size_t)mh * 16 + w) * 2);
  }
  __syncthreads();
  const int o = tid & 63;
  const int ng = tid >> 6;
  float2 acc[4] = {{0.f,0.f},{0.f,0.f},{0.f,0.f},{0.f,0.f}};
  for (int i = 0; i < ICH; ++i) {
    float2 wv = wsld[i * OCH + o];
#pragma unroll
    for (int q = 0; q < 4; ++q) {
      float2 bv = bs[(ng * 4 + q) * ICH + i];
      acc[q].x += bv.x * wv.x - bv.y * wv.y;
      acc[q].y += bv.x * wv.y + bv.y * wv.x;
    }
  }
#pragma unroll
  for (int q = 0; q < 4; ++q) {
    int n = ng * 4 + q;
    BC[(((size_t)n * TMODES + t) * MODES + w) * ICH + o] = acc[q];
  }
}

// ---------------- Stage 4: inverse y-DFT via MFMA (M-stacked complex) ----------------
// Dstack(256x64) = E2(256x64) @ Cstack(64x64) per (n,w).
// E2 rows m<128: Dre[y=m] = [cos | -sin]; m>=128: Dim[y=m-128] = [sin | cos].
__global__ __launch_bounds__(512) void k_idfty(const float2* __restrict__ C,
                                               float2* __restrict__ D) {
  const int n = blockIdx.x >> 4;
  const int w = blockIdx.x & 15;
  __shared__ float2 ut[128];
  __shared__ ushort E2[256][72];
  __shared__ ushort Cs[64][72];  // [o][k], k = t + 32*plane
  const int tid = threadIdx.x;
  if (tid < 128) {
    float s, c;
    sincosf(PI2F * (float)tid * (1.0f / 128.0f), &s, &c);
    ut[tid] = make_float2(c, s);
  }
  __syncthreads();
#pragma unroll
  for (int e = 0; e < 32; ++e) {
    int idx = e * 512 + tid;           // 16384 entries
    int m = idx >> 6, k = idx & 63;
    int y = m & 127, imr = m >> 7;
    int t = k & 31, pl = k >> 5;
    int h = (t < 16) ? t : (t + 96);
    float2 u = ut[(h * y) & 127];
    float val;
    if (!imr) val = pl ? -u.y : u.x;   // [cos | -sin]
    else      val = pl ? u.x : u.y;    // [sin | cos]
    E2[m][k] = f2bf(val);
  }
  const float sc = (w == 0) ? (1.f / 16384.f) : (2.f / 16384.f);
#pragma unroll
  for (int e = 0; e < 4; ++e) {
    int idx = e * 512 + tid;           // 2048 float2 of C
    int t = idx & 31, o = idx >> 5;
    float2 v = C[(((size_t)n * TMODES + t) * MODES + w) * ICH + o];
    Cs[o][t] = f2bf(v.x * sc);
    Cs[o][t + 32] = f2bf(v.y * sc);
  }
  __syncthreads();
  const int wid = tid >> 6, lane = tid & 63;
  const int lr = lane & 15, lk = lane >> 4;
  f32x4 acc[2][4];
#pragma unroll
  for (int mi = 0; mi < 2; ++mi)
#pragma unroll
    for (int nt = 0; nt < 4; ++nt) acc[mi][nt] = (f32x4)(0.f);
#pragma unroll
  for (int kt = 0; kt < 2; ++kt) {
    int kb = kt * 32 + lk * 8;
    bf16x8 b[4];
#pragma unroll
    for (int nt = 0; nt < 4; ++nt) b[nt] = *(const bf16x8*)&Cs[nt * 16 + lr][kb];
#pragma unroll
    for (int mi = 0; mi < 2; ++mi) {
      bf16x8 a = *(const bf16x8*)&E2[(wid * 2 + mi) * 16 + lr][kb];
#pragma unroll
      for (int nt = 0; nt < 4; ++nt)
        acc[mi][nt] = __builtin_amdgcn_mfma_f32_16x16x32_bf16(a, b[nt], acc[mi][nt], 0, 0, 0);
    }
  }
  float* Df = (float*)D;
#pragma unroll
  for (int mi = 0; mi < 2; ++mi)
#pragma unroll
    for (int nt = 0; nt < 4; ++nt)
#pragma unroll
      for (int q = 0; q < 4; ++q) {
        int m = (wid * 2 + mi) * 16 + lk * 4 + q;
        int y = m & 127, pl = m >> 7;
        int o = nt * 16 + lr;
        Df[((((size_t)n * RSZ + y) * MODES + w) * OCH + o) * 2 + pl] = acc[mi][nt][q];
      }
}

// ---------------- Stage 5: fused [X|E] @ [WresT;Dsc] + bias + SiLU (MFMA) ----------------
__global__ __launch_bounds__(256) void k_final(const float* __restrict__ X,
                                               const float2* __restrict__ D,
                                               const float* __restrict__ w_res,
                                               const float* __restrict__ b_res,
                                               float* __restrict__ out) {
  __shared__ ushort Ac[128][104];
  __shared__ ushort Bc[64][104];
  __shared__ float br[64];
  const int tid = threadIdx.x;
  const int row = blockIdx.x;
  const float* Xr = X + (size_t)row * RSZ * ICH;
#pragma unroll
  for (int j = 0; j < 8; ++j) {
    int k = tid + j * 256;
    int x = k >> 4, i0 = (k & 15) * 4;
    float4 v = *(const float4*)&Xr[x * ICH + i0];
    ushort4 pk;
    pk.x = f2bf(v.x); pk.y = f2bf(v.y); pk.z = f2bf(v.z); pk.w = f2bf(v.w);
    *(ushort4*)&Ac[x][i0] = pk;
  }
  {
    int x = tid >> 1, half = tid & 1;
#pragma unroll
    for (int w2 = 0; w2 < 8; ++w2) {
      int w = half * 8 + w2;
      int p = (w * x) & 127;
      float s, c;
      sincosf(PI2F * (float)p * (1.0f / 128.0f), &s, &c);
      Ac[x][64 + 2 * w] = f2bf(c);
      Ac[x][64 + 2 * w + 1] = f2bf(-s);
    }
  }
#pragma unroll
  for (int j = 0; j < 4; ++j) {
    int k = tid + j * 256;
    int i = k >> 4, o0 = (k & 15) * 4;
    float4 v = *(const float4*)&w_res[i * OCH + o0];
    Bc[o0 + 0][i] = f2bf(v.x);
    Bc[o0 + 1][i] = f2bf(v.y);
    Bc[o0 + 2][i] = f2bf(v.z);
    Bc[o0 + 3][i] = f2bf(v.w);
  }
#pragma unroll
  for (int j = 0; j < 4; ++j) {
    int k = tid + j * 256;
    int w = k >> 6, o = k & 63;
    float2 d = D[((size_t)row * MODES + w) * OCH + o];
    ushort2 pk;
    pk.x = f2bf(d.x); pk.y = f2bf(d.y);
    *(ushort2*)&Bc[o][64 + 2 * w] = pk;
  }
  if (tid < 64) br[tid] = b_res[tid];
  __syncthreads();
  const int wid = tid >> 6, lane = tid & 63;
  const int lr = lane & 15, lk = lane >> 4;
  f32x4 acc[2][4];
#pragma unroll
  for (int mi = 0; mi < 2; ++mi)
#pragma unroll
    for (int nt = 0; nt < 4; ++nt) acc[mi][nt] = (f32x4)(0.f);
#pragma unroll
  for (int kt = 0; kt < 3; ++kt) {
    int kb = kt * 32 + lk * 8;
    bf16x8 a0 = *(const bf16x8*)&Ac[(wid * 2 + 0) * 16 + lr][kb];
    bf16x8 a1 = *(const bf16x8*)&Ac[(wid * 2 + 1) * 16 + lr][kb];
    bf16x8 b[4];
#pragma unroll
    for (int nt = 0; nt < 4; ++nt) b[nt] = *(const bf16x8*)&Bc[nt * 16 + lr][kb];
#pragma unroll
    for (int nt = 0; nt < 4; ++nt) {
      acc[0][nt] = __builtin_amdgcn_mfma_f32_16x16x32_bf16(a0, b[nt], acc[0][nt], 0, 0, 0);
      acc[1][nt] = __builtin_amdgcn_mfma_f32_16x16x32_bf16(a1, b[nt], acc[1][nt], 0, 0, 0);
    }
  }
  float* orow = out + (size_t)row * RSZ * OCH;
#pragma unroll
  for (int mi = 0; mi < 2; ++mi)
#pragma unroll
    for (int nt = 0; nt < 4; ++nt)
#pragma unroll
      for (int q = 0; q < 4; ++q) {
        int x = (wid * 2 + mi) * 16 + lk * 4 + q;
        int o = nt * 16 + lr;
        float v = acc[mi][nt][q] + br[o];
        orow[x * OCH + o] = v / (1.f + __expf(-v));
      }
}

extern "C" void kernel_launch(void* const* d_in, const int* in_sizes, int n_in,
                              void* d_out, int out_size, void* d_ws, size_t ws_size,
                              hipStream_t stream) {
  (void)in_sizes; (void)n_in; (void)out_size; (void)ws_size;
  const float* X = (const float*)d_in[0];
  const float* w_res = (const float*)d_in[1];
  const float* b_res = (const float*)d_in[2];
  const float* fw0 = (const float*)d_in[3];
  const float* fw1 = (const float*)d_in[4];
  float* out = (float*)d_out;
  float* wsf = (float*)d_ws;
  const size_t PLANE = (size_t)NBATCH * RSZ * MODES * ICH;
  float* Are = wsf;
  float* Aim = wsf + PLANE;
  float2* bufB = (float2*)(wsf + 2 * PLANE);
  float2* Dbuf = (float2*)wsf;
  k_dftx<<<NBATCH * RSZ / 4, 256, 0, stream>>>(X, Are, Aim);
  k_dfty<<<NBATCH * MODES, 512, 0, stream>>>(Are, Aim, bufB);
  k_mix<<<TMODES * MODES, 256, 0, stream>>>(bufB, fw0, fw1);
  k_idfty<<<NBATCH * MODES, 512, 0, stream>>>(bufB, Dbuf);
  k_final<<<NBATCH * RSZ, 256, 0, stream>>>(X, Dbuf, w_res, b_res, out);
}

// Round 4
// 69.561 us; speedup vs baseline: 2.5535x; 1.3193x over previous
//
#include <hip/hip_runtime.h>

#define NBATCH 16
#define RSZ 128
#define ICH 64
#define OCH 64
#define MODES 16
#define TMODES 32
#define PI2F 6.283185307179586f

typedef float f32x4 __attribute__((ext_vector_type(4)));
typedef short bf16x8 __attribute__((ext_vector_type(8)));

static __device__ __forceinline__ ushort f2bf(float f) {
  union { float f; unsigned u; } v;
  v.f = f;
  unsigned r = v.u + 0x7FFFu + ((v.u >> 16) & 1u);
  return (ushort)(r >> 16);
}
static __device__ __forceinline__ float b2f(ushort u) {
  union { unsigned u; float f; } v;
  v.u = ((unsigned)u) << 16;
  return v.f;
}

// Table sub-offsets inside `tabs` (ushort units)
#define TAB_TM 0            // [32][128]
#define TAB_EF 4096         // [128][32]
#define TAB_WR 8192         // [64][64]  wrT[o][i]
#define TAB_T1 12288        // [64][256]
#define TAB_E2 28672        // [256][64]
// total 45056 ushorts

// ---------------- Stage 0: prep (fw transpose->bf16, twiddle tables) ----------------
__global__ __launch_bounds__(256) void k_prep(const float* __restrict__ fw0,
                                              const float* __restrict__ fw1,
                                              const float* __restrict__ w_res,
                                              ushort* __restrict__ fwT,
                                              ushort* __restrict__ tabs) {
  const int b = blockIdx.x;
  const int tid = threadIdx.x;
  if (b < 128) {
    // fwT[w][t][i][o][c] <- fw{0,1}[i][o][mh][w][c]
    const int tensor = b >> 6, i = b & 63;
    const float* fw = tensor ? fw1 : fw0;
    const int o = tid & 63, q = tid >> 6;  // q: mh quarter
    const float2* src = (const float2*)fw + ((size_t)(i * 64 + o) * 256 + q * 64);
    ushort2* dst = (ushort2*)fwT;
#pragma unroll 4
    for (int r = 0; r < 64; ++r) {  // r = mh_local*16 + w
      float2 v = src[r];
      int mh = q * 4 + (r >> 4), w = r & 15;
      int t = tensor * 16 + mh;
      ushort2 pk;
      pk.x = f2bf(v.x);
      pk.y = f2bf(v.y);
      dst[(((size_t)w * 32 + t) * 64 + i) * 64 + o] = pk;
    }
    return;
  }
  __shared__ float2 ut[128];
  if (tid < 128) {
    float s, c;
    sincosf(PI2F * (float)tid * (1.0f / 128.0f), &s, &c);
    ut[tid] = make_float2(c, s);
  }
  __syncthreads();
  if (b == 128) {  // Tm[m=2w+c][x]
    for (int e = tid; e < 4096; e += 256) {
      int m = e >> 7, x = e & 127, w = m >> 1, c = m & 1;
      float2 u = ut[(w * x) & 127];
      tabs[TAB_TM + e] = f2bf(c ? -u.y : u.x);
    }
  } else if (b == 129) {  // Ef[x][2w+c]
    for (int e = tid; e < 4096; e += 256) {
      int x = e >> 5, mm = e & 31, w = mm >> 1, c = mm & 1;
      float2 u = ut[(w * x) & 127];
      tabs[TAB_EF + e] = f2bf(c ? -u.y : u.x);
    }
  } else if (b == 130) {  // wrT[o][i]
    for (int e = tid; e < 4096; e += 256) {
      int o = e >> 6, i = e & 63;
      tabs[TAB_WR + e] = f2bf(w_res[i * 64 + o]);
    }
  } else if (b < 135) {  // T1[64][256]
    for (int k = tid; k < 4096; k += 256) {
      int e = (b - 131) * 4096 + k;
      int m = e >> 8, kk = e & 255;
      int y = kk & 127, pl = kk >> 7;
      int t = m & 31, imr = m >> 5;
      int h = (t < 16) ? t : (t + 96);
      float2 u = ut[(h * y) & 127];
      float val = (!imr) ? (pl ? u.y : u.x) : (pl ? u.x : -u.y);
      tabs[TAB_T1 + e] = f2bf(val);
    }
  } else {  // b 135..138: E2[256][64]
    for (int k = tid; k < 4096; k += 256) {
      int e = (b - 135) * 4096 + k;
      int m = e >> 6, kk = e & 63;
      int y = m & 127, imr = m >> 7;
      int t = kk & 31, pl = kk >> 5;
      int h = (t < 16) ? t : (t + 96);
      float2 u = ut[(h * y) & 127];
      float val = (!imr) ? (pl ? -u.y : u.x) : (pl ? u.x : u.y);
      tabs[TAB_E2 + e] = f2bf(val);
    }
  }
}

// ---------------- Stage 1: partial DFT along x (MFMA), A out bf16 ----------------
__global__ __launch_bounds__(256) void k_dftx(const float* __restrict__ X,
                                              const ushort* __restrict__ tabs,
                                              ushort* __restrict__ Are,
                                              ushort* __restrict__ Aim) {
  __shared__ ushort Tm[32][136];
  __shared__ ushort XT[4][64][136];
  const int tid = threadIdx.x;
  const int row0 = blockIdx.x * 4;
  {
    int m = tid >> 3, seg = (tid & 7) * 16;
    *(bf16x8*)&Tm[m][seg] = *(const bf16x8*)&tabs[TAB_TM + m * 128 + seg];
    *(bf16x8*)&Tm[m][seg + 8] = *(const bf16x8*)&tabs[TAB_TM + m * 128 + seg + 8];
  }
  {
    const int rr = tid >> 6, lane = tid & 63;
    const float* Xr = X + (size_t)(row0 + rr) * RSZ * ICH;
    for (int j = 0; j < 8; ++j) {
      int t = lane + 64 * j;
      int i0 = (t & 15) * 4, x0 = (t >> 4) * 4;
      float4 r0 = *(const float4*)&Xr[(x0 + 0) * ICH + i0];
      float4 r1 = *(const float4*)&Xr[(x0 + 1) * ICH + i0];
      float4 r2 = *(const float4*)&Xr[(x0 + 2) * ICH + i0];
      float4 r3 = *(const float4*)&Xr[(x0 + 3) * ICH + i0];
#pragma unroll
      for (int p = 0; p < 4; ++p) {
        int i = i0 + p;
        int col = x0 ^ ((((i) >> 2) & 7) << 3);
        ushort4 pk;
        pk.x = f2bf(((const float*)&r0)[p]);
        pk.y = f2bf(((const float*)&r1)[p]);
        pk.z = f2bf(((const float*)&r2)[p]);
        pk.w = f2bf(((const float*)&r3)[p]);
        *(ushort4*)&XT[rr][i][col] = pk;
      }
    }
  }
  __syncthreads();
  const int wid = tid >> 6, lane = tid & 63;
  const int lr = lane & 15, lk = lane >> 4;
  f32x4 acc[2][4];
#pragma unroll
  for (int mt = 0; mt < 2; ++mt)
#pragma unroll
    for (int nt = 0; nt < 4; ++nt) acc[mt][nt] = (f32x4)(0.f);
#pragma unroll
  for (int kt = 0; kt < 4; ++kt) {
    int kb = kt * 32 + lk * 8;
    bf16x8 a0 = *(const bf16x8*)&Tm[lr][kb];
    bf16x8 a1 = *(const bf16x8*)&Tm[16 + lr][kb];
    bf16x8 b[4];
#pragma unroll
    for (int nt = 0; nt < 4; ++nt) {
      int i = nt * 16 + lr;
      int col = kb ^ (((i >> 2) & 7) << 3);
      b[nt] = *(const bf16x8*)&XT[wid][i][col];
    }
#pragma unroll
    for (int nt = 0; nt < 4; ++nt) {
      acc[0][nt] = __builtin_amdgcn_mfma_f32_16x16x32_bf16(a0, b[nt], acc[0][nt], 0, 0, 0);
      acc[1][nt] = __builtin_amdgcn_mfma_f32_16x16x32_bf16(a1, b[nt], acc[1][nt], 0, 0, 0);
    }
  }
  const int row = row0 + wid;
#pragma unroll
  for (int mt = 0; mt < 2; ++mt)
#pragma unroll
    for (int q = 0; q < 4; ++q) {
      int m = mt * 16 + lk * 4 + q;
      int w = m >> 1, c = m & 1;
      ushort* plane = c ? Aim : Are;
#pragma unroll
      for (int nt = 0; nt < 4; ++nt) {
        int i = nt * 16 + lr;
        plane[((size_t)row * MODES + w) * ICH + i] = f2bf(acc[mt][nt][q]);
      }
    }
}

// ---------------- Stage 2: y-DFT via MFMA, B out bf16 [n][t][w][i][c] ----------------
__global__ __launch_bounds__(512) void k_dfty(const ushort* __restrict__ Are,
                                              const ushort* __restrict__ Aim,
                                              const ushort* __restrict__ tabs,
                                              ushort* __restrict__ B) {
  const int n = blockIdx.x >> 4;
  const int w = blockIdx.x & 15;
  __shared__ ushort T1[64][264];
  __shared__ ushort As[64][264];  // [i][k], k = y + 128*plane
  const int tid = threadIdx.x;
  {
    int m = tid >> 3, seg = (tid & 7) * 32;
#pragma unroll
    for (int e = 0; e < 4; ++e)
      *(bf16x8*)&T1[m][seg + e * 8] = *(const bf16x8*)&tabs[TAB_T1 + m * 256 + seg + e * 8];
  }
#pragma unroll
  for (int e = 0; e < 2; ++e) {
    int tt = e * 512 + tid;
    int pl = tt >> 9, r = tt & 511;
    int i0 = (r & 15) * 4, y0 = (r >> 4) * 4;
    const ushort* P = pl ? Aim : Are;
    const ushort* base = P + (((size_t)(n * RSZ + y0) * MODES + w) * ICH + i0);
    ushort4 r0 = *(const ushort4*)(base + 0 * MODES * ICH);
    ushort4 r1 = *(const ushort4*)(base + 1 * MODES * ICH);
    ushort4 r2 = *(const ushort4*)(base + 2 * MODES * ICH);
    ushort4 r3 = *(const ushort4*)(base + 3 * MODES * ICH);
    const ushort* q0 = (const ushort*)&r0;
    const ushort* q1 = (const ushort*)&r1;
    const ushort* q2 = (const ushort*)&r2;
    const ushort* q3 = (const ushort*)&r3;
#pragma unroll
    for (int p = 0; p < 4; ++p) {
      ushort4 pk;
      pk.x = q0[p]; pk.y = q1[p]; pk.z = q2[p]; pk.w = q3[p];
      *(ushort4*)&As[i0 + p][pl * 128 + y0] = pk;
    }
  }
  __syncthreads();
  const int wid = tid >> 6, lane = tid & 63;
  const int lr = lane & 15, lk = lane >> 4;
  const int mt = wid >> 1, nh = wid & 1;
  f32x4 acc[2];
  acc[0] = (f32x4)(0.f);
  acc[1] = (f32x4)(0.f);
#pragma unroll
  for (int kt = 0; kt < 8; ++kt) {
    int kb = kt * 32 + lk * 8;
    bf16x8 a = *(const bf16x8*)&T1[mt * 16 + lr][kb];
    bf16x8 b0 = *(const bf16x8*)&As[(nh * 2 + 0) * 16 + lr][kb];
    bf16x8 b1 = *(const bf16x8*)&As[(nh * 2 + 1) * 16 + lr][kb];
    acc[0] = __builtin_amdgcn_mfma_f32_16x16x32_bf16(a, b0, acc[0], 0, 0, 0);
    acc[1] = __builtin_amdgcn_mfma_f32_16x16x32_bf16(a, b1, acc[1], 0, 0, 0);
  }
#pragma unroll
  for (int nt2 = 0; nt2 < 2; ++nt2)
#pragma unroll
    for (int q = 0; q < 4; ++q) {
      int m = mt * 16 + lk * 4 + q;
      int t = m & 31, pl = m >> 5;
      int i = (nh * 2 + nt2) * 16 + lr;
      B[(((size_t)n * TMODES + t) * MODES + w) * 128 + i * 2 + pl] = f2bf(acc[nt2][q]);
    }
}

// ---------------- Stage 3: mode mixing (in-place on B, bf16) ----------------
__global__ __launch_bounds__(256) void k_mix(ushort* __restrict__ BC,
                                             const ushort* __restrict__ fwT) {
  const int t = blockIdx.x >> 4;
  const int w = blockIdx.x & 15;
  __shared__ float2 bs[NBATCH * ICH];
  __shared__ float2 wsld[ICH * OCH];
  const int tid = threadIdx.x;
  for (int k = tid; k < NBATCH * ICH; k += 256) {
    int n = k >> 6, i = k & 63;
    ushort2 v = *(const ushort2*)&BC[(((size_t)n * TMODES + t) * MODES + w) * 128 + i * 2];
    bs[k] = make_float2(b2f(v.x), b2f(v.y));
  }
  {
    const ushort* Wsl = fwT + ((size_t)(w * 32 + t)) * 8192;
    for (int k4 = tid; k4 < 1024; k4 += 256) {
      bf16x8 v = *(const bf16x8*)(Wsl + k4 * 8);
#pragma unroll
      for (int e = 0; e < 4; ++e)
        wsld[k4 * 4 + e] = make_float2(b2f((ushort)v[2 * e]), b2f((ushort)v[2 * e + 1]));
    }
  }
  __syncthreads();
  const int o = tid & 63;
  const int ng = tid >> 6;
  float2 acc[4] = {{0.f,0.f},{0.f,0.f},{0.f,0.f},{0.f,0.f}};
  for (int i = 0; i < ICH; ++i) {
    float2 wv = wsld[i * OCH + o];
#pragma unroll
    for (int q = 0; q < 4; ++q) {
      float2 bv = bs[(ng * 4 + q) * ICH + i];
      acc[q].x += bv.x * wv.x - bv.y * wv.y;
      acc[q].y += bv.x * wv.y + bv.y * wv.x;
    }
  }
#pragma unroll
  for (int q = 0; q < 4; ++q) {
    int n = ng * 4 + q;
    ushort2 pk;
    pk.x = f2bf(acc[q].x);
    pk.y = f2bf(acc[q].y);
    *(ushort2*)&BC[(((size_t)n * TMODES + t) * MODES + w) * 128 + o * 2] = pk;
  }
}

// ---------------- Stage 4: inverse y-DFT via MFMA, D out bf16 [row][w][o][c] ----------------
__global__ __launch_bounds__(512) void k_idfty(const ushort* __restrict__ C,
                                               const ushort* __restrict__ tabs,
                                               ushort* __restrict__ D) {
  const int n = blockIdx.x >> 4;
  const int w = blockIdx.x & 15;
  __shared__ ushort E2[256][72];
  __shared__ ushort Cs[64][72];  // [o][k], k = t + 32*plane
  const int tid = threadIdx.x;
  {
    int m = tid >> 1, seg = (tid & 1) * 32;
#pragma unroll
    for (int e = 0; e < 4; ++e)
      *(bf16x8*)&E2[m][seg + e * 8] = *(const bf16x8*)&tabs[TAB_E2 + m * 64 + seg + e * 8];
  }
  const float sc = (w == 0) ? (1.f / 16384.f) : (2.f / 16384.f);
#pragma unroll
  for (int e = 0; e < 4; ++e) {
    int idx = e * 512 + tid;  // 2048 = 64 o x 32 t
    int o = idx & 63, t = idx >> 6;
    ushort2 v = *(const ushort2*)&C[(((size_t)n * TMODES + t) * MODES + w) * 128 + o * 2];
    Cs[o][t] = f2bf(b2f(v.x) * sc);
    Cs[o][t + 32] = f2bf(b2f(v.y) * sc);
  }
  __syncthreads();
  const int wid = tid >> 6, lane = tid & 63;
  const int lr = lane & 15, lk = lane >> 4;
  f32x4 acc[2][4];
#pragma unroll
  for (int mi = 0; mi < 2; ++mi)
#pragma unroll
    for (int nt = 0; nt < 4; ++nt) acc[mi][nt] = (f32x4)(0.f);
#pragma unroll
  for (int kt = 0; kt < 2; ++kt) {
    int kb = kt * 32 + lk * 8;
    bf16x8 b[4];
#pragma unroll
    for (int nt = 0; nt < 4; ++nt) b[nt] = *(const bf16x8*)&Cs[nt * 16 + lr][kb];
#pragma unroll
    for (int mi = 0; mi < 2; ++mi) {
      bf16x8 a = *(const bf16x8*)&E2[(wid * 2 + mi) * 16 + lr][kb];
#pragma unroll
      for (int nt = 0; nt < 4; ++nt)
        acc[mi][nt] = __builtin_amdgcn_mfma_f32_16x16x32_bf16(a, b[nt], acc[mi][nt], 0, 0, 0);
    }
  }
#pragma unroll
  for (int mi = 0; mi < 2; ++mi)
#pragma unroll
    for (int nt = 0; nt < 4; ++nt)
#pragma unroll
      for (int q = 0; q < 4; ++q) {
        int m = (wid * 2 + mi) * 16 + lk * 4 + q;
        int y = m & 127, pl = m >> 7;
        int o = nt * 16 + lr;
        D[((size_t)(n * RSZ + y) * MODES + w) * 128 + o * 2 + pl] = f2bf(acc[mi][nt][q]);
      }
}

// ---------------- Stage 5: fused [X|E] @ [WresT;Dsc] + bias + SiLU (MFMA) ----------------
__global__ __launch_bounds__(256) void k_final(const float* __restrict__ X,
                                               const ushort* __restrict__ D,
                                               const ushort* __restrict__ tabs,
                                               const float* __restrict__ b_res,
                                               float* __restrict__ out) {
  __shared__ ushort Ac[128][104];
  __shared__ ushort Bc[64][104];
  __shared__ float br[64];
  const int tid = threadIdx.x;
  const int row = blockIdx.x;
  const float* Xr = X + (size_t)row * RSZ * ICH;
#pragma unroll
  for (int j = 0; j < 8; ++j) {
    int k = tid + j * 256;
    int x = k >> 4, i0 = (k & 15) * 4;
    float4 v = *(const float4*)&Xr[x * ICH + i0];
    ushort4 pk;
    pk.x = f2bf(v.x); pk.y = f2bf(v.y); pk.z = f2bf(v.z); pk.w = f2bf(v.w);
    *(ushort4*)&Ac[x][i0] = pk;
  }
  {
    int x = tid >> 1, half = tid & 1;
    *(bf16x8*)&Ac[x][64 + half * 16] = *(const bf16x8*)&tabs[TAB_EF + x * 32 + half * 16];
    *(bf16x8*)&Ac[x][64 + half * 16 + 8] = *(const bf16x8*)&tabs[TAB_EF + x * 32 + half * 16 + 8];
  }
  {
    int o = tid >> 2, s = (tid & 3) * 16;
    *(bf16x8*)&Bc[o][s] = *(const bf16x8*)&tabs[TAB_WR + o * 64 + s];
    *(bf16x8*)&Bc[o][s + 8] = *(const bf16x8*)&tabs[TAB_WR + o * 64 + s + 8];
  }
#pragma unroll
  for (int j = 0; j < 4; ++j) {
    int idx = tid + j * 256;
    int w2 = idx >> 6, o = idx & 63;
    ushort2 v = *(const ushort2*)&D[(size_t)row * 2048 + w2 * 128 + o * 2];
    *(ushort2*)&Bc[o][64 + 2 * w2] = v;
  }
  if (tid < 64) br[tid] = b_res[tid];
  __syncthreads();
  const int wid = tid >> 6, lane = tid & 63;
  const int lr = lane & 15, lk = lane >> 4;
  f32x4 acc[2][4];
#pragma unroll
  for (int mi = 0; mi < 2; ++mi)
#pragma unroll
    for (int nt = 0; nt < 4; ++nt) acc[mi][nt] = (f32x4)(0.f);
#pragma unroll
  for (int kt = 0; kt < 3; ++kt) {
    int kb = kt * 32 + lk * 8;
    bf16x8 a0 = *(const bf16x8*)&Ac[(wid * 2 + 0) * 16 + lr][kb];
    bf16x8 a1 = *(const bf16x8*)&Ac[(wid * 2 + 1) * 16 + lr][kb];
    bf16x8 b[4];
#pragma unroll
    for (int nt = 0; nt < 4; ++nt) b[nt] = *(const bf16x8*)&Bc[nt * 16 + lr][kb];
#pragma unroll
    for (int nt = 0; nt < 4; ++nt) {
      acc[0][nt] = __builtin_amdgcn_mfma_f32_16x16x32_bf16(a0, b[nt], acc[0][nt], 0, 0, 0);
      acc[1][nt] = __builtin_amdgcn_mfma_f32_16x16x32_bf16(a1, b[nt], acc[1][nt], 0, 0, 0);
    }
  }
  float* orow = out + (size_t)row * RSZ * OCH;
#pragma unroll
  for (int mi = 0; mi < 2; ++mi)
#pragma unroll
    for (int nt = 0; nt < 4; ++nt)
#pragma unroll
      for (int q = 0; q < 4; ++q) {
        int x = (wid * 2 + mi) * 16 + lk * 4 + q;
        int o = nt * 16 + lr;
        float v = acc[mi][nt][q] + br[o];
        orow[x * OCH + o] = v / (1.f + __expf(-v));
      }
}

extern "C" void kernel_launch(void* const* d_in, const int* in_sizes, int n_in,
                              void* d_out, int out_size, void* d_ws, size_t ws_size,
                              hipStream_t stream) {
  (void)in_sizes; (void)n_in; (void)out_size; (void)ws_size;
  const float* X = (const float*)d_in[0];
  const float* w_res = (const float*)d_in[1];
  const float* b_res = (const float*)d_in[2];
  const float* fw0 = (const float*)d_in[3];
  const float* fw1 = (const float*)d_in[4];
  float* out = (float*)d_out;
  ushort* wsu = (ushort*)d_ws;
  ushort* Are = wsu;                    // 2,097,152
  ushort* Aim = Are + 2097152;          // 2,097,152
  ushort* Bbf = Aim + 2097152;          // 1,048,576  (B, mixed in place -> C)
  ushort* Dbf = Bbf + 1048576;          // 4,194,304
  ushort* fwT = Dbf + 4194304;          // 4,194,304
  ushort* tabs = fwT + 4194304;         // 45,056
  k_prep<<<139, 256, 0, stream>>>(fw0, fw1, w_res, fwT, tabs);
  k_dftx<<<NBATCH * RSZ / 4, 256, 0, stream>>>(X, tabs, Are, Aim);
  k_dfty<<<NBATCH * MODES, 512, 0, stream>>>(Are, Aim, tabs, Bbf);
  k_mix<<<TMODES * MODES, 256, 0, stream>>>(Bbf, fwT);
  k_idfty<<<NBATCH * MODES, 512, 0, stream>>>(Bbf, tabs, Dbf);
  k_final<<<NBATCH * RSZ, 256, 0, stream>>>(X, Dbf, tabs, b_res, out);
}